// Round 11
// baseline (90.928 us; speedup 1.0000x reference)
//
#include <hip/hip_runtime.h>

#define NLAT 192
#define NPTS 40320
#define MMAX 96
#define LMAX 96
#define NV   100
#define MAXN 400
#define NB   400   // total B rows = 4 * NV

typedef __attribute__((ext_vector_type(8))) _Float16 half8v;  // 8 f16 (4 VGPRs)
typedef __attribute__((ext_vector_type(4))) float f32x4;

#define FSTR 40   // K2 LDS row stride (shorts)

static __device__ __forceinline__ float bits2f(unsigned int b) {
    union { unsigned int i; float f; } v; v.i = b; return v.f;
}
static __device__ __forceinline__ unsigned int f2bf(float f) {
    union { float f; unsigned int i; } v; v.f = f;
    return (v.i + 0x7FFFu + ((v.i >> 16) & 1u)) >> 16;
}
static __device__ __forceinline__ unsigned short f2h(float f) {
    _Float16 h = (_Float16)f;
    union { _Float16 h; unsigned short s; } u; u.h = h; return u.s;
}
static __device__ __forceinline__ float h2f(unsigned short s) {
    union { _Float16 h; unsigned short s; } u; u.s = s; return (float)u.h;
}

// S(n) = sum_{t<n} floor(t/8)
static __device__ __forceinline__ int Ssum(int n) {
    int q = n >> 3, r = n & 7; return 4 * q * (q - 1) + q * r;
}
// padded-32 k-units before ring j in At (ragged layout); total = 43008
static __device__ __forceinline__ int atoffk(int j) {
    if (j < 96) return 32 * (Ssum(j + 12) - 4);
    return 32 * (672 + 676 - Ssum(204 - j));
}
static __device__ __forceinline__ int kpad_of(int j) {
    return 32 * ((j < 96 ? (j + 12) : (203 - j)) >> 3);
}

// ---------------- K0a: split leg fp32 -> f16 hi/lo, relayout [l][m][j] -> [m][l][j]
__global__ __launch_bounds__(256) void leg_conv_kernel(
    const float* __restrict__ leg,    // [96 l][96 m][192 j]
    unsigned short* __restrict__ legh,
    unsigned short* __restrict__ legl)
{
    int idx = blockIdx.x * 256 + threadIdx.x;
    if (idx >= 96 * 96 * 192) return;
    int j = idx % 192;
    int lm = idx / 192;
    int m = lm % 96, l = lm / 96;
    float v = leg[idx];
    unsigned short h = f2h(v);
    unsigned short lo = f2h(v - h2f(h));
    size_t o = ((size_t)m * 96 + l) * 192 + j;
    legh[o] = h;
    legl[o] = lo;
}

// ---------------- K0b: transpose dft words into At (f16), k-step-blocked:
// At[j]: per k-step t, contiguous [192 rows][32 k] f16 (12288 B)
// rows: mm = m (re) / 96+m (im); k padded to x32 with zeros.
__global__ __launch_bounds__(256) void dft_transpose_kernel(
    const unsigned int* __restrict__ dftw,   // [192][400][96] (bf16 re | im<<16)
    unsigned short* __restrict__ At)
{
    const int j = blockIdx.x;
    const int kpad = kpad_of(j);
    const int t = blockIdx.y;
    const int k0 = t * 32;
    if (k0 >= kpad) return;
    const int n = j < 96 ? 20 + 4 * j : 400 - 4 * (j - 96);
    unsigned short* abase = At + (size_t)atoffk(j) * 192 + (size_t)t * 6144;
    const int tid = threadIdx.x;
#pragma unroll
    for (int s = 0; s < 3; ++s) {
        int slot = s * 256 + tid;          // 768 = 192 rows x 4 chunks
        int row = slot % 192;
        int ch  = slot / 192;
        int m = row < 96 ? row : row - 96;
        bool isIm = row >= 96;
        const unsigned int* dp = dftw + ((size_t)j * MAXN + k0 + ch * 8) * 96 + m;
        unsigned short o[8];
#pragma unroll
        for (int i = 0; i < 8; ++i) {
            int k = k0 + ch * 8 + i;
            unsigned int v = (k < n) ? dp[(size_t)i * 96] : 0u;
            float f = isIm ? bits2f(v & 0xFFFF0000u) : bits2f(v << 16);
            o[i] = f2h(f);
        }
        uint4 pk;
        pk.x = (unsigned int)o[0] | ((unsigned int)o[1] << 16);
        pk.y = (unsigned int)o[2] | ((unsigned int)o[3] << 16);
        pk.z = (unsigned int)o[4] | ((unsigned int)o[5] << 16);
        pk.w = (unsigned int)o[6] | ((unsigned int)o[7] << 16);
        *(uint4*)(abase + (size_t)row * 32 + ch * 8) = pk;
    }
}

// ---------------- K1 (MFMA f16): ring DFT GEMM.
// A-fragments load DIRECTLY from global (coalesced 1KB/wave, L2-resident, no
// LDS, no DMA-drain at barriers). X staged in dbuf LDS (XOR swizzle both
// sides); X global loads issued one step early (stay in flight across MFMA).
// fh[j][mm][B] f16 single plane = sum_k At[j][mm][k] * x[B][k] (x = hi+lo f16)
__global__ __launch_bounds__(256) void dft_mfma_kernel(
    const float* __restrict__ data,          // [4][NPTS][NV] fp32
    const unsigned short* __restrict__ At,   // ragged [j][t][192][32] f16
    unsigned short* __restrict__ fh,         // [NLAT][192][cn] f16
    int c0, int cn)
{
    __shared__ unsigned short Xh_lds[2][64 * 32];
    __shared__ unsigned short Xl_lds[2][64 * 32];

    const int id  = blockIdx.x;
    const int j   = id % 192;                // same-ring blocks -> same XCD
    const int bt  = id / 192;
    const int tid = threadIdx.x;
    const int w   = tid >> 6;
    const int l   = tid & 63;
    const int lr  = l & 15;
    const int kg  = l >> 4;
    const int kgp = kg ^ ((lr >> 1) & 3);    // swizzled frag chunk

    int n, start;
    if (j < 96) { n = 20 + 4 * j; start = 2 * j * j + 18 * j; }
    else { int jj = j - 96; n = 400 - 4 * jj; start = 20160 + 402 * jj - 2 * jj * jj; }
    const int nsteps = kpad_of(j) >> 5;
    const unsigned short* abase = At + (size_t)atoffk(j) * 192;

    const int Bb = c0 + bt * 50;
    const int bb = Bb / NV;
    const int vb = Bb % NV;
    const float* dbase = data + (size_t)bb * NPTS * NV + vb;

    const int xc  = tid >> 2;                // X staging: B col 0..63
    const int xch = tid & 3;                 // logical k chunk
    const int xpc = xch ^ ((xc >> 1) & 3);   // phys chunk (same involution)

    f32x4 acc[3][4];
#pragma unroll
    for (int i = 0; i < 3; ++i)
#pragma unroll
        for (int nt = 0; nt < 4; ++nt) acc[i][nt] = (f32x4){0.f, 0.f, 0.f, 0.f};

    float xv[8];

    // ---- prologue: stage X step 0 into buf 0
    {
        const float* sp = dbase + (size_t)(start + xch * 8) * NV + xc;
#pragma unroll
        for (int i = 0; i < 8; ++i) {
            int k = xch * 8 + i;
            xv[i] = (xc < 50 && k < n) ? sp[(size_t)i * NV] : 0.f;
        }
        unsigned int hw[4], lw[4];
#pragma unroll
        for (int t2 = 0; t2 < 4; ++t2) {
            unsigned short h0 = f2h(xv[2 * t2]), h1 = f2h(xv[2 * t2 + 1]);
            unsigned short l0 = f2h(xv[2 * t2] - h2f(h0));
            unsigned short l1 = f2h(xv[2 * t2 + 1] - h2f(h1));
            hw[t2] = (unsigned int)h0 | ((unsigned int)h1 << 16);
            lw[t2] = (unsigned int)l0 | ((unsigned int)l1 << 16);
        }
        *(uint4*)&Xh_lds[0][xc * 32 + xpc * 8] = (uint4){hw[0], hw[1], hw[2], hw[3]};
        *(uint4*)&Xl_lds[0][xc * 32 + xpc * 8] = (uint4){lw[0], lw[1], lw[2], lw[3]};
        __syncthreads();
    }

    int buf = 0;
    for (int t = 0; t < nsteps; ++t) {
        const int nb = buf ^ 1;
        const bool pf = (t + 1 < nsteps);

        // issue next-step X global loads early (hide HBM under MFMA)
        if (pf) {
            const float* sp = dbase + (size_t)(start + (t + 1) * 32 + xch * 8) * NV + xc;
#pragma unroll
            for (int i = 0; i < 8; ++i) {
                int k = (t + 1) * 32 + xch * 8 + i;
                xv[i] = (xc < 50 && k < n) ? sp[(size_t)i * NV] : 0.f;
            }
        }

        // A-fragments: direct global reads (wave covers contiguous 1KB; L2-hit)
        const half8v* av = (const half8v*)(abase + (size_t)t * 6144);
        half8v a0 = av[((3 * w + 0) * 16 + lr) * 4 + kg];
        half8v a1 = av[((3 * w + 1) * 16 + lr) * 4 + kg];
        half8v a2 = av[((3 * w + 2) * 16 + lr) * 4 + kg];

#pragma unroll
        for (int nt = 0; nt < 4; ++nt) {
            half8v bh = *(const half8v*)&Xh_lds[buf][(nt * 16 + lr) * 32 + kgp * 8];
            half8v bl = *(const half8v*)&Xl_lds[buf][(nt * 16 + lr) * 32 + kgp * 8];
            acc[0][nt] = __builtin_amdgcn_mfma_f32_16x16x32_f16(a0, bh, acc[0][nt], 0, 0, 0);
            acc[1][nt] = __builtin_amdgcn_mfma_f32_16x16x32_f16(a1, bh, acc[1][nt], 0, 0, 0);
            acc[2][nt] = __builtin_amdgcn_mfma_f32_16x16x32_f16(a2, bh, acc[2][nt], 0, 0, 0);
            acc[0][nt] = __builtin_amdgcn_mfma_f32_16x16x32_f16(a0, bl, acc[0][nt], 0, 0, 0);
            acc[1][nt] = __builtin_amdgcn_mfma_f32_16x16x32_f16(a1, bl, acc[1][nt], 0, 0, 0);
            acc[2][nt] = __builtin_amdgcn_mfma_f32_16x16x32_f16(a2, bl, acc[2][nt], 0, 0, 0);
        }

        // convert + write next-step X into nb (after MFMA reads of buf)
        if (pf) {
            unsigned int hw[4], lw[4];
#pragma unroll
            for (int t2 = 0; t2 < 4; ++t2) {
                unsigned short h0 = f2h(xv[2 * t2]), h1 = f2h(xv[2 * t2 + 1]);
                unsigned short l0 = f2h(xv[2 * t2] - h2f(h0));
                unsigned short l1 = f2h(xv[2 * t2 + 1] - h2f(h1));
                hw[t2] = (unsigned int)h0 | ((unsigned int)h1 << 16);
                lw[t2] = (unsigned int)l0 | ((unsigned int)l1 << 16);
            }
            *(uint4*)&Xh_lds[nb][xc * 32 + xpc * 8] = (uint4){hw[0], hw[1], hw[2], hw[3]};
            *(uint4*)&Xl_lds[nb][xc * 32 + xpc * 8] = (uint4){lw[0], lw[1], lw[2], lw[3]};
        }
        __syncthreads();
        buf = nb;
    }

    // ---- epilogue: C/D col=lane&15 (B), row=(lane>>4)*4+reg (mm); emit f16
#pragma unroll
    for (int i = 0; i < 3; ++i)
#pragma unroll
        for (int nt = 0; nt < 4; ++nt) {
            int c = nt * 16 + lr;
            if (c < 50) {
                int Brel = bt * 50 + c;
                int mm0 = (3 * w + i) * 16 + kg * 4;
                unsigned short* oh = fh + ((size_t)j * 192 + mm0) * cn + Brel;
#pragma unroll
                for (int r = 0; r < 4; ++r)
                    oh[(size_t)r * cn] = f2h(acc[i][nt][r]);
            }
        }
}

// ---------------- K2 (MFMA f16): Legendre contraction per m.
// C[l, B] = sum_j leg[l,m,j] * fh[j, m+96pl, B]; leg = hi+lo f16, F = f16.
__global__ __launch_bounds__(256) void leg_mfma_kernel(
    const unsigned short* __restrict__ legh,  // [96 m][96 l][192 j] f16
    const unsigned short* __restrict__ legl,
    const unsigned short* __restrict__ fh,    // [192 j][192 mm][cn] f16
    unsigned int* __restrict__ out,           // [4][LMAX][MMAX][NV] packed bf16
    int c0, int cn)
{
    __shared__ unsigned short A_lds[2 * 96 * FSTR];   // [hl][l][k]
    __shared__ unsigned short F_lds[2 * 64 * FSTR];   // [pl][B][k]

    const int m   = blockIdx.x;
    const int bt  = blockIdx.y;
    const int tid = threadIdx.x;
    const int w   = tid >> 6;
    const int l   = tid & 63;
    const int lr  = l & 15;
    const int kg  = l >> 4;

    f32x4 acc[6][2];
#pragma unroll
    for (int lt = 0; lt < 6; ++lt)
#pragma unroll
        for (int pl = 0; pl < 2; ++pl) acc[lt][pl] = (f32x4){0.f, 0.f, 0.f, 0.f};

    const unsigned int* lh32 = (const unsigned int*)legh;
    const unsigned int* ll32 = (const unsigned int*)legl;
    const unsigned int* f32p = (const unsigned int*)fh;

    for (int j0 = 0; j0 < NLAT; j0 += 32) {
        __syncthreads();

        // stage A: [2 hl][96 l][32 k]; s<6 -> hi plane, s>=6 -> lo (6*256=1536)
#pragma unroll
        for (int s = 0; s < 12; ++s) {
            const int hl = (s >= 6) ? 1 : 0;
            int rem = tid + 256 * s - 1536 * hl;   // 0..1535
            int lrow = rem >> 4;
            int ku = rem & 15;
            const unsigned int* src = hl ? ll32 : lh32;
            unsigned int v = src[((size_t)m * 96 + lrow) * 96 + (j0 >> 1) + ku];
            ((unsigned int*)A_lds)[(size_t)hl * 96 * (FSTR / 2) + lrow * (FSTR / 2) + ku] = v;
        }

        // stage F: [2 pl][64 B][32 k]  (1600 uints; B cols 50..63 stale-dont-care)
#pragma unroll
        for (int s = 0; s < 7; ++s) {
            int q = tid + 256 * s;
            if (q < 1600) {
                int u  = q % 25;                 // B-pair
                int r2 = q / 25;                 // 0..63
                int jj = r2 & 31;
                int pl = r2 >> 5;
                unsigned int v = f32p[((size_t)(j0 + jj) * 192 + m + 96 * pl) * (cn >> 1)
                                      + bt * 25 + u];
                size_t base = ((size_t)pl * 64 + 2 * u) * FSTR + jj;
                F_lds[base]        = (unsigned short)(v & 0xFFFFu);
                F_lds[base + FSTR] = (unsigned short)(v >> 16);
            }
        }
        __syncthreads();

        half8v fF[2];
#pragma unroll
        for (int pl = 0; pl < 2; ++pl)
            fF[pl] = *(const half8v*)&F_lds[((size_t)pl * 64 + w * 16 + lr) * FSTR + kg * 8];
#pragma unroll
        for (int lt = 0; lt < 6; ++lt) {
            half8v ah = *(const half8v*)&A_lds[(size_t)(0 * 96 + lt * 16 + lr) * FSTR + kg * 8];
            half8v al = *(const half8v*)&A_lds[(size_t)(1 * 96 + lt * 16 + lr) * FSTR + kg * 8];
#pragma unroll
            for (int pl = 0; pl < 2; ++pl) {
                acc[lt][pl] = __builtin_amdgcn_mfma_f32_16x16x32_f16(ah, fF[pl], acc[lt][pl], 0, 0, 0);
                acc[lt][pl] = __builtin_amdgcn_mfma_f32_16x16x32_f16(al, fF[pl], acc[lt][pl], 0, 0, 0);
            }
        }
    }

    int c = w * 16 + lr;
    if (c < 50) {
        int B = c0 + bt * 50 + c;
        int bb = B / NV, vv = B % NV;
#pragma unroll
        for (int lt = 0; lt < 6; ++lt) {
#pragma unroll
            for (int r = 0; r < 4; ++r) {
                int ll = lt * 16 + kg * 4 + r;
                out[(((size_t)bb * LMAX + ll) * MMAX + m) * NV + vv] =
                    f2bf(acc[lt][0][r]) | (f2bf(acc[lt][1][r]) << 16);
            }
        }
    }
}

extern "C" void kernel_launch(void* const* d_in, const int* in_sizes, int n_in,
                              void* d_out, int out_size, void* d_ws, size_t ws_size,
                              hipStream_t stream) {
    if (n_in != 3) return;

    const float* data = (const float*)d_in[0];
    const unsigned int* dftw = (const unsigned int*)d_in[1];
    const float* leg  = (const float*)d_in[2];
    unsigned int* out = (unsigned int*)d_out;

    // ws: [legh][legl][At][fh]
    const size_t LEGN = (size_t)96 * 96 * 192;
    const size_t LEGB = 2 * LEGN * sizeof(unsigned short);   // 7.08 MB
    const size_t ATN  = (size_t)43008 * 192;                 // shorts
    const size_t ATB  = ATN * sizeof(unsigned short);        // 16.5 MB
    const size_t rowb = (size_t)192 * 192 * sizeof(unsigned short); // 73728 B / B-row
    if (ws_size < LEGB + ATB + 50 * rowb) return;

    unsigned short* legh = (unsigned short*)d_ws;
    unsigned short* legl = legh + LEGN;
    unsigned short* At   = legl + LEGN;

    size_t maxrows = (ws_size - LEGB - ATB) / rowb;
    int chunk = (int)((maxrows / 50) * 50);
    if (chunk > NB) chunk = NB;

    leg_conv_kernel<<<dim3((96 * 96 * 192 + 255) / 256), dim3(256), 0, stream>>>(
        leg, legh, legl);
    dft_transpose_kernel<<<dim3(192, 13), dim3(256), 0, stream>>>(dftw, At);

    for (int c0 = 0; c0 < NB; c0 += chunk) {
        int cn = NB - c0 < chunk ? NB - c0 : chunk;
        unsigned short* fh = At + ATN;

        int nbt = cn / 50;
        dim3 g1(192 * nbt);
        dft_mfma_kernel<<<g1, dim3(256), 0, stream>>>(data, At, fh, c0, cn);
        dim3 g2(96, nbt);
        leg_mfma_kernel<<<g2, dim3(256), 0, stream>>>(legh, legl, fh, out, c0, cn);
    }
}